// Round 1
// baseline (10285.573 us; speedup 1.0000x reference)
//
#include <hip/hip_runtime.h>

// Problem constants (fixed by the reference)
#define BD 8
#define SD 4096
#define DDIM 512
#define QD 8
#define CDN 1024
#define ROWS (BD * SD)              // 32768
#define QUANT_ELEMS (ROWS * DDIM)   // 16777216
#define IDX_ELEMS (ROWS * QD)       // 262144
#define IDX_OFF QUANT_ELEMS
#define LOSS_OFF (QUANT_ELEMS + IDX_ELEMS)

// argmin tiling
#define RPB 64                      // rows per block
#define CPT 128                     // codes per tile
#define DCC 32                      // d-chunk
#define NDC (DDIM / DCC)            // 16
#define NCT (CDN / CPT)             // 8
#define LSTR (DCC + 4)              // LDS row stride (36 floats, 16B-aligned rows)

// ws layout: [0..64) loss doubles, [256..256+32KiB) norms, [64KiB ...) residual
#define WS_NORM_OFF 256
#define WS_RESID_OFF 65536

// ---------------------------------------------------------------- norms
__global__ __launch_bounds__(256) void vq_norms(const float* __restrict__ cb,
                                                float* __restrict__ norms) {
    int code = blockIdx.x * 4 + (threadIdx.x >> 6);  // one wave per code
    int lane = threadIdx.x & 63;
    const float4* p = (const float4*)(cb + (size_t)code * DDIM);
    float4 a = p[lane];
    float4 b = p[lane + 64];
    float s = a.x * a.x + a.y * a.y + a.z * a.z + a.w * a.w +
              b.x * b.x + b.y * b.y + b.z * b.z + b.w * b.w;
#pragma unroll
    for (int m = 32; m >= 1; m >>= 1) s += __shfl_xor(s, m);
    if (lane == 0) norms[code] = s;
}

// ---------------------------------------------------------------- argmin
// dist[c] = ||c||^2 - 2 <r, c>; fused argmin with first-index tie-break.
__global__ __launch_bounds__(256, 2) void vq_argmin(
    const float* __restrict__ rsrc, const float* __restrict__ qsub,
    const float* __restrict__ cbq, const float* __restrict__ normq,
    float* __restrict__ idx_out, int q) {
    __shared__ float cb_s[CPT][LSTR];
    __shared__ float r_s[RPB][LSTR];

    int tid = threadIdx.x;
    int tx = tid & 15;   // -> codes
    int ty = tid >> 4;   // -> rows
    int row0 = blockIdx.x * RPB;

    float bd[4];
    int bi[4];
#pragma unroll
    for (int i = 0; i < 4; i++) { bd[i] = 3.4e38f; bi[i] = 0; }

    for (int ct = 0; ct < NCT; ct++) {
        int cbase = ct * CPT;
        float acc[4][8];
#pragma unroll
        for (int ri = 0; ri < 4; ri++)
#pragma unroll
            for (int cj = 0; cj < 8; cj++) acc[ri][cj] = 0.0f;

        for (int dc = 0; dc < NDC; dc++) {
            int d0 = dc * DCC;
            __syncthreads();
            // stage codebook tile: 128 codes x 32 dims (coalesced, conflict-min stores)
#pragma unroll
            for (int i = 0; i < 4; i++) {
                int u = tid + 256 * i;          // 0..1023
                int code = u >> 3;
                int dd4 = (u & 7) * 4;
                float4 v = *(const float4*)(cbq + (size_t)(cbase + code) * DDIM + d0 + dd4);
                *(float4*)&cb_s[code][dd4] = v;
            }
            // stage residual tile: 64 rows x 32 dims
#pragma unroll
            for (int i = 0; i < 2; i++) {
                int u = tid + 256 * i;          // 0..511
                int row = u >> 3;
                int dd4 = (u & 7) * 4;
                size_t g = (size_t)(row0 + row) * DDIM + d0 + dd4;
                float4 v = *(const float4*)(rsrc + g);
                if (qsub) {
                    float4 w = *(const float4*)(qsub + g);
                    v.x -= w.x; v.y -= w.y; v.z -= w.z; v.w -= w.w;
                }
                *(float4*)&r_s[row][dd4] = v;
            }
            __syncthreads();

#pragma unroll
            for (int dk = 0; dk < DCC / 4; dk++) {
                int d = dk * 4;
                float4 a[4], b[8];
#pragma unroll
                for (int ri = 0; ri < 4; ri++) a[ri] = *(const float4*)&r_s[ty * 4 + ri][d];
#pragma unroll
                for (int j = 0; j < 4; j++) b[j] = *(const float4*)&cb_s[tx * 4 + j][d];
#pragma unroll
                for (int j = 0; j < 4; j++) b[4 + j] = *(const float4*)&cb_s[64 + tx * 4 + j][d];
#pragma unroll
                for (int ri = 0; ri < 4; ri++) {
#pragma unroll
                    for (int cj = 0; cj < 8; cj++) {
                        float s = acc[ri][cj];
                        s = fmaf(a[ri].x, b[cj].x, s);
                        s = fmaf(a[ri].y, b[cj].y, s);
                        s = fmaf(a[ri].z, b[cj].z, s);
                        s = fmaf(a[ri].w, b[cj].w, s);
                        acc[ri][cj] = s;
                    }
                }
            }
        }

        // distances + running argmin for this code tile
        float4 n0 = *(const float4*)(normq + cbase + tx * 4);
        float4 n1 = *(const float4*)(normq + cbase + 64 + tx * 4);
        float nrm[8] = {n0.x, n0.y, n0.z, n0.w, n1.x, n1.y, n1.z, n1.w};
        int cid[8];
#pragma unroll
        for (int j = 0; j < 4; j++) {
            cid[j] = cbase + tx * 4 + j;
            cid[4 + j] = cbase + 64 + tx * 4 + j;
        }
#pragma unroll
        for (int ri = 0; ri < 4; ri++) {
            float d_ = nrm[0] - 2.0f * acc[ri][0];
            int i_ = cid[0];
#pragma unroll
            for (int j = 1; j < 8; j++) {
                float dj = nrm[j] - 2.0f * acc[ri][j];
                if (dj < d_ || (dj == d_ && cid[j] < i_)) { d_ = dj; i_ = cid[j]; }
            }
            // butterfly over the 16 tx-lanes (same ty group)
#pragma unroll
            for (int m = 1; m <= 8; m <<= 1) {
                float od = __shfl_xor(d_, m);
                int oi = __shfl_xor(i_, m);
                if (od < d_ || (od == d_ && oi < i_)) { d_ = od; i_ = oi; }
            }
            if (d_ < bd[ri] || (d_ == bd[ri] && i_ < bi[ri])) { bd[ri] = d_; bi[ri] = i_; }
        }
    }

    if (tx == 0) {
#pragma unroll
        for (int ri = 0; ri < 4; ri++) {
            int row = row0 + ty * 4 + ri;
            idx_out[(size_t)row * QD + q] = (float)bi[ri];
        }
    }
}

// ---------------------------------------------------------------- update
// residual_new = r - cb[idx]; quant += cb[idx]; loss_q += sum(residual_new^2)
__global__ __launch_bounds__(256) void vq_update(
    const float* __restrict__ rsrc, const float* __restrict__ qsub,
    float* __restrict__ resid, float* __restrict__ quant,
    const float* __restrict__ idx_arr, const float* __restrict__ cbq,
    double* __restrict__ lossq, int q) {
    int tid = threadIdx.x;
    int row = blockIdx.x * 2 + (tid >> 7);
    int c4 = (tid & 127) * 4;
    size_t e = (size_t)row * DDIM + c4;

    int idx = (int)idx_arr[(size_t)row * QD + q];
    float4 cv = *(const float4*)(cbq + (size_t)idx * DDIM + c4);
    float4 r = *(const float4*)(rsrc + e);
    if (qsub) {
        float4 w = *(const float4*)(qsub + e);
        r.x -= w.x; r.y -= w.y; r.z -= w.z; r.w -= w.w;
    }
    float4 nr;
    nr.x = r.x - cv.x; nr.y = r.y - cv.y; nr.z = r.z - cv.z; nr.w = r.w - cv.w;
    if (resid) *(float4*)(resid + e) = nr;
    float4 qo = *(float4*)(quant + e);
    qo.x += cv.x; qo.y += cv.y; qo.z += cv.z; qo.w += cv.w;
    *(float4*)(quant + e) = qo;

    double s = (double)nr.x * nr.x + (double)nr.y * nr.y +
               (double)nr.z * nr.z + (double)nr.w * nr.w;
#pragma unroll
    for (int m = 32; m >= 1; m >>= 1) s += __shfl_down(s, m);
    __shared__ double partial[4];
    if ((tid & 63) == 0) partial[tid >> 6] = s;
    __syncthreads();
    if (tid == 0) atomicAdd(lossq, partial[0] + partial[1] + partial[2] + partial[3]);
}

// ---------------------------------------------------------------- finalize
__global__ void vq_loss_final(const double* __restrict__ lossws, float* __restrict__ out) {
    int i = threadIdx.x;
    if (i < QD) out[i] = (float)(lossws[i] * (1.0 / (double)((size_t)ROWS * DDIM)));
}

// ---------------------------------------------------------------- launch
extern "C" void kernel_launch(void* const* d_in, const int* in_sizes, int n_in,
                              void* d_out, int out_size, void* d_ws, size_t ws_size,
                              hipStream_t stream) {
    const float* x = (const float*)d_in[0];
    const float* cbs = (const float*)d_in[1];
    float* out = (float*)d_out;
    float* quant = out;
    float* idxo = out + IDX_OFF;
    float* losso = out + LOSS_OFF;

    double* lossws = (double*)d_ws;
    float* norms = (float*)((char*)d_ws + WS_NORM_OFF);
    size_t residNeed = (size_t)WS_RESID_OFF + (size_t)QUANT_ELEMS * 4;
    float* resid = (ws_size >= residNeed) ? (float*)((char*)d_ws + WS_RESID_OFF) : nullptr;

    hipMemsetAsync(d_out, 0, (size_t)out_size * 4, stream);
    hipMemsetAsync(d_ws, 0, 64, stream);

    vq_norms<<<QD * CDN / 4, 256, 0, stream>>>(cbs, norms);

    for (int q = 0; q < QD; q++) {
        const float* cbq = cbs + (size_t)q * CDN * DDIM;
        const float* nq = norms + (size_t)q * CDN;
        const float* rsrc;
        const float* qsubA;
        if (resid) {
            rsrc = (q == 0) ? x : resid;
            qsubA = nullptr;
        } else {
            rsrc = x;
            qsubA = quant;  // r = x - quant (quant zeroed at start)
        }
        vq_argmin<<<ROWS / RPB, 256, 0, stream>>>(rsrc, qsubA, cbq, nq, idxo, q);
        vq_update<<<ROWS / 2, 256, 0, stream>>>(rsrc, qsubA, resid, quant, idxo, cbq,
                                                lossws + q, q);
    }
    vq_loss_final<<<1, 64, 0, stream>>>(lossws, losso);
}

// Round 2
// 7177.279 us; speedup vs baseline: 1.4331x; 1.4331x over previous
//
#include <hip/hip_runtime.h>

// Problem constants (fixed by the reference)
#define BD 8
#define SD 4096
#define DDIM 512
#define QD 8
#define CDN 1024
#define ROWS (BD * SD)              // 32768
#define QUANT_ELEMS (ROWS * DDIM)   // 16777216
#define IDX_OFF QUANT_ELEMS
#define LOSS_OFF (QUANT_ELEMS + ROWS * QD)

// argmin tiling
#define TPB 512
#define RPB 64                      // rows per block
#define CPT 256                     // codes per tile
#define NCT (CDN / CPT)             // 4
#define DCC 32                      // d-chunk
#define NDC (DDIM / DCC)            // 16
#define LSTR 36                     // LDS row stride in floats (16B aligned rows)

// ws layout: [0..64) loss doubles, [256..256+32KiB) norms, [64KiB ...) residual
#define WS_NORM_OFF 256
#define WS_RESID_OFF 65536

// ---------------------------------------------------------------- norms
__global__ __launch_bounds__(256) void vq_norms(const float* __restrict__ cb,
                                                float* __restrict__ norms) {
    int code = blockIdx.x * 4 + (threadIdx.x >> 6);  // one wave per code
    int lane = threadIdx.x & 63;
    const float4* p = (const float4*)(cb + (size_t)code * DDIM);
    float4 a = p[lane];
    float4 b = p[lane + 64];
    float s = a.x * a.x + a.y * a.y + a.z * a.z + a.w * a.w +
              b.x * b.x + b.y * b.y + b.z * b.z + b.w * b.w;
#pragma unroll
    for (int m = 32; m >= 1; m >>= 1) s += __shfl_xor(s, m);
    if (lane == 0) norms[code] = s;
}

// ---------------------------------------------------------------- fused level
// Phase 1: dist[c] = ||c||^2 - 2<r,c>, fused argmin (first-index tie-break).
// Phase 2: residual update in-place + commit-loss partial sum.
// Lane mapping: tx = tid&31 -> codes (code = cbase + tx + 32*j, conflict-free
// LDS quads since bank start = (4*tx + d) mod 32), ty = tid>>5 -> rows (4 each).
__global__ __launch_bounds__(TPB, 4) void vq_level(
    const float* __restrict__ rsrc, const float* __restrict__ qsub,
    float* __restrict__ resid, float* __restrict__ quant,
    const float* __restrict__ cbq, const float* __restrict__ normq,
    float* __restrict__ idx_out, double* __restrict__ lossq, int q) {
    __shared__ float cb_s[CPT][LSTR];   // 36864 B
    __shared__ float r_s[RPB][LSTR];    // 9216 B
    __shared__ int s_idx[RPB];
    __shared__ double s_part[8];

    int tid = threadIdx.x;
    int tx = tid & 31;    // -> codes
    int ty = tid >> 5;    // -> row groups (0..15)
    int row0 = blockIdx.x * RPB;

    float bd[4];
    int bi[4];
#pragma unroll
    for (int i = 0; i < 4; i++) { bd[i] = 3.4e38f; bi[i] = 0; }

    // staging address precompute
    int st_row = tid >> 3;            // 0..63
    int st_d4 = (tid & 7) * 4;        // 0..28

    for (int ct = 0; ct < NCT; ct++) {
        int cbase = ct * CPT;
        float acc[4][8];
#pragma unroll
        for (int ri = 0; ri < 4; ri++)
#pragma unroll
            for (int cj = 0; cj < 8; cj++) acc[ri][cj] = 0.0f;

        for (int dc = 0; dc < NDC; dc++) {
            int d0 = dc * DCC;
            __syncthreads();
            // stage codebook tile: 256 codes x 32 dims (2048 float4, 4/thread)
#pragma unroll
            for (int i = 0; i < 4; i++) {
                int u = tid + TPB * i;           // 0..2047
                int code = u >> 3;
                int dd4 = (u & 7) * 4;
                float4 v = *(const float4*)(cbq + (size_t)(cbase + code) * DDIM + d0 + dd4);
                *(float4*)&cb_s[code][dd4] = v;
            }
            // stage residual tile: 64 rows x 32 dims (512 float4, 1/thread)
            {
                size_t g = (size_t)(row0 + st_row) * DDIM + d0 + st_d4;
                float4 v = *(const float4*)(rsrc + g);
                if (qsub) {
                    float4 w = *(const float4*)(qsub + g);
                    v.x -= w.x; v.y -= w.y; v.z -= w.z; v.w -= w.w;
                }
                *(float4*)&r_s[st_row][st_d4] = v;
            }
            __syncthreads();

#pragma unroll
            for (int dk = 0; dk < DCC / 4; dk++) {
                int d = dk * 4;
                float4 a[4], b[8];
#pragma unroll
                for (int ri = 0; ri < 4; ri++) a[ri] = *(const float4*)&r_s[ty * 4 + ri][d];
#pragma unroll
                for (int j = 0; j < 8; j++) b[j] = *(const float4*)&cb_s[tx + 32 * j][d];
#pragma unroll
                for (int ri = 0; ri < 4; ri++) {
#pragma unroll
                    for (int cj = 0; cj < 8; cj++) {
                        float s = acc[ri][cj];
                        s = fmaf(a[ri].x, b[cj].x, s);
                        s = fmaf(a[ri].y, b[cj].y, s);
                        s = fmaf(a[ri].z, b[cj].z, s);
                        s = fmaf(a[ri].w, b[cj].w, s);
                        acc[ri][cj] = s;
                    }
                }
            }
        }

        // distances + running argmin for this code tile
        float nrm[8];
        int cid[8];
#pragma unroll
        for (int j = 0; j < 8; j++) {
            cid[j] = cbase + tx + 32 * j;
            nrm[j] = normq[cid[j]];
        }
#pragma unroll
        for (int ri = 0; ri < 4; ri++) {
            float d_ = nrm[0] - 2.0f * acc[ri][0];
            int i_ = cid[0];
#pragma unroll
            for (int j = 1; j < 8; j++) {      // ascending code index: tie -> lower
                float dj = nrm[j] - 2.0f * acc[ri][j];
                if (dj < d_ || (dj == d_ && cid[j] < i_)) { d_ = dj; i_ = cid[j]; }
            }
            // butterfly over the 32 tx-lanes (bit5 = ty parity untouched)
#pragma unroll
            for (int m = 1; m <= 16; m <<= 1) {
                float od = __shfl_xor(d_, m);
                int oi = __shfl_xor(i_, m);
                if (od < d_ || (od == d_ && oi < i_)) { d_ = od; i_ = oi; }
            }
            if (d_ < bd[ri] || (d_ == bd[ri] && i_ < bi[ri])) { bd[ri] = d_; bi[ri] = i_; }
        }
    }

    if (tx == 0) {
#pragma unroll
        for (int ri = 0; ri < 4; ri++) {
            int row = ty * 4 + ri;
            s_idx[row] = bi[ri];
            idx_out[(size_t)(row0 + row) * QD + q] = (float)bi[ri];
        }
    }
    __syncthreads();

    // ---- update phase: resid_new = r - cb[idx]; loss += ||resid_new||^2
    double ls = 0.0;
#pragma unroll 4
    for (int i = 0; i < 16; i++) {
        int flat = tid + TPB * i;          // 0..8191 float4 chunks
        int row = flat >> 7;               // 128 float4 per row
        int c4 = (flat & 127) * 4;
        size_t g = (size_t)(row0 + row) * DDIM + c4;
        float4 r = *(const float4*)(rsrc + g);
        if (qsub) {
            float4 w = *(const float4*)(qsub + g);
            r.x -= w.x; r.y -= w.y; r.z -= w.z; r.w -= w.w;
        }
        float4 cv = *(const float4*)(cbq + (size_t)s_idx[row] * DDIM + c4);
        float4 nr;
        nr.x = r.x - cv.x; nr.y = r.y - cv.y; nr.z = r.z - cv.z; nr.w = r.w - cv.w;
        if (resid) {
            *(float4*)(resid + g) = nr;
        } else {
            float4 qo = *(float4*)(quant + g);
            qo.x += cv.x; qo.y += cv.y; qo.z += cv.z; qo.w += cv.w;
            *(float4*)(quant + g) = qo;
        }
        ls += (double)nr.x * nr.x + (double)nr.y * nr.y +
              (double)nr.z * nr.z + (double)nr.w * nr.w;
    }
#pragma unroll
    for (int m = 32; m >= 1; m >>= 1) ls += __shfl_down(ls, m);
    if ((tid & 63) == 0) s_part[tid >> 6] = ls;
    __syncthreads();
    if (tid == 0) {
        double t = 0.0;
#pragma unroll
        for (int w = 0; w < 8; w++) t += s_part[w];
        atomicAdd(lossq, t);
    }
}

// ---------------------------------------------------------------- quant = x - resid_final
__global__ __launch_bounds__(256) void vq_quant_final(const float* __restrict__ x,
                                                      const float* __restrict__ resid,
                                                      float* __restrict__ quant) {
    size_t i = ((size_t)blockIdx.x * 256 + threadIdx.x) * 4;
    float4 xv = *(const float4*)(x + i);
    float4 rv = *(const float4*)(resid + i);
    float4 o;
    o.x = xv.x - rv.x; o.y = xv.y - rv.y; o.z = xv.z - rv.z; o.w = xv.w - rv.w;
    *(float4*)(quant + i) = o;
}

// ---------------------------------------------------------------- finalize losses
__global__ void vq_loss_final(const double* __restrict__ lossws, float* __restrict__ out) {
    int i = threadIdx.x;
    if (i < QD) out[i] = (float)(lossws[i] * (1.0 / (double)((size_t)ROWS * DDIM)));
}

// ---------------------------------------------------------------- launch
extern "C" void kernel_launch(void* const* d_in, const int* in_sizes, int n_in,
                              void* d_out, int out_size, void* d_ws, size_t ws_size,
                              hipStream_t stream) {
    const float* x = (const float*)d_in[0];
    const float* cbs = (const float*)d_in[1];
    float* out = (float*)d_out;
    float* quant = out;
    float* idxo = out + IDX_OFF;
    float* losso = out + LOSS_OFF;

    double* lossws = (double*)d_ws;
    float* norms = (float*)((char*)d_ws + WS_NORM_OFF);
    size_t residNeed = (size_t)WS_RESID_OFF + (size_t)QUANT_ELEMS * 4;
    float* resid = (ws_size >= residNeed) ? (float*)((char*)d_ws + WS_RESID_OFF) : nullptr;

    hipMemsetAsync(d_ws, 0, 64, stream);
    if (!resid) hipMemsetAsync(d_out, 0, (size_t)out_size * 4, stream);

    vq_norms<<<QD * CDN / 4, 256, 0, stream>>>(cbs, norms);

    for (int q = 0; q < QD; q++) {
        const float* cbq = cbs + (size_t)q * CDN * DDIM;
        const float* nq = norms + (size_t)q * CDN;
        const float* rsrc;
        const float* qsubA;
        if (resid) {
            rsrc = (q == 0) ? x : resid;
            qsubA = nullptr;
        } else {
            rsrc = x;
            qsubA = quant;  // r = x - quant (quant zeroed at start)
        }
        vq_level<<<ROWS / RPB, TPB, 0, stream>>>(rsrc, qsubA,
                                                 resid ? resid : nullptr, quant,
                                                 cbq, nq, idxo, lossws + q, q);
    }
    if (resid) {
        vq_quant_final<<<QUANT_ELEMS / 1024, 256, 0, stream>>>(x, resid, quant);
    }
    vq_loss_final<<<1, 64, 0, stream>>>(lossws, losso);
}

// Round 3
// 5445.242 us; speedup vs baseline: 1.8889x; 1.3181x over previous
//
#include <hip/hip_runtime.h>

// Problem constants (fixed by the reference)
#define BD 8
#define SD 4096
#define DDIM 512
#define QD 8
#define CDN 1024
#define ROWS (BD * SD)              // 32768
#define QUANT_ELEMS (ROWS * DDIM)   // 16777216
#define IDX_OFF QUANT_ELEMS
#define LOSS_OFF (QUANT_ELEMS + ROWS * QD)

// argmin tiling
#define TPB 512
#define RPB 64                      // rows per block
#define CPT 256                     // codes per tile
#define NCT (CDN / CPT)             // 4
#define DCC 32                      // d-chunk
#define NDC (DDIM / DCC)            // 16
#define LSTR 36                     // LDS row stride in floats (16B aligned rows)

// ws layout: [0..64) loss doubles, [256..256+32KiB) norms, [64KiB ...) residual
#define WS_NORM_OFF 256
#define WS_RESID_OFF 65536

// ---------------------------------------------------------------- norms
__global__ __launch_bounds__(256) void vq_norms(const float* __restrict__ cb,
                                                float* __restrict__ norms) {
    int code = blockIdx.x * 4 + (threadIdx.x >> 6);  // one wave per code
    int lane = threadIdx.x & 63;
    const float4* p = (const float4*)(cb + (size_t)code * DDIM);
    float4 a = p[lane];
    float4 b = p[lane + 64];
    float s = a.x * a.x + a.y * a.y + a.z * a.z + a.w * a.w +
              b.x * b.x + b.y * b.y + b.z * b.z + b.w * b.w;
#pragma unroll
    for (int m = 32; m >= 1; m >>= 1) s += __shfl_xor(s, m);
    if (lane == 0) norms[code] = s;
}

// ---------------------------------------------------------------- fused level
// Phase 1: dist[c] = ||c||^2 - 2<r,c>, fused argmin (first-index tie-break).
// Phase 2: residual update in-place + commit-loss partial sum.
// tx = tid&31 -> codes (code = cbase + tx + 32*j: LDS bank quad = (tx + d/4)
// mod 8, unique per 8 consecutive lanes). ty = tid>>5 -> 4 rows each.
// __launch_bounds__(512,2): min 2 waves/EU -> 256-VGPR cap; compiler lands
// ~115 -> 4 waves/SIMD, NO scratch spills (R2's (512,4) made the compiler
// target 8 waves/EU = 64 VGPRs -> 3 GB/dispatch of spill traffic).
__global__ __launch_bounds__(TPB, 2) void vq_level(
    const float* __restrict__ rsrc, const float* __restrict__ qsub,
    float* __restrict__ resid, float* __restrict__ quant,
    const float* __restrict__ cbq, const float* __restrict__ normq,
    float* __restrict__ idx_out, double* __restrict__ lossq, int q) {
    __shared__ float cb_s[CPT][LSTR];   // 36864 B
    __shared__ float r_s[RPB][LSTR];    // 9216 B
    __shared__ int s_idx[RPB];
    __shared__ double s_part[8];

    int tid = threadIdx.x;
    int tx = tid & 31;    // -> codes
    int ty = tid >> 5;    // -> row groups (0..15)
    int row0 = blockIdx.x * RPB;

    float bd[4];
    int bi[4];
#pragma unroll
    for (int i = 0; i < 4; i++) { bd[i] = 3.4e38f; bi[i] = 0; }

    // staging address precompute
    int st_row = tid >> 3;            // 0..63
    int st_d4 = (tid & 7) * 4;        // 0..28

    for (int ct = 0; ct < NCT; ct++) {
        int cbase = ct * CPT;
        float acc[4][8];
#pragma unroll
        for (int ri = 0; ri < 4; ri++)
#pragma unroll
            for (int cj = 0; cj < 8; cj++) acc[ri][cj] = 0.0f;

        for (int dc = 0; dc < NDC; dc++) {
            int d0 = dc * DCC;
            __syncthreads();
            // stage codebook tile: 256 codes x 32 dims (2048 float4, 4/thread)
#pragma unroll
            for (int i = 0; i < 4; i++) {
                int u = tid + TPB * i;           // 0..2047
                int code = u >> 3;
                int dd4 = (u & 7) * 4;
                float4 v = *(const float4*)(cbq + (size_t)(cbase + code) * DDIM + d0 + dd4);
                *(float4*)&cb_s[code][dd4] = v;
            }
            // stage residual tile: 64 rows x 32 dims (512 float4, 1/thread)
            {
                size_t g = (size_t)(row0 + st_row) * DDIM + d0 + st_d4;
                float4 v = *(const float4*)(rsrc + g);
                if (qsub) {
                    float4 w = *(const float4*)(qsub + g);
                    v.x -= w.x; v.y -= w.y; v.z -= w.z; v.w -= w.w;
                }
                *(float4*)&r_s[st_row][st_d4] = v;
            }
            __syncthreads();

#pragma unroll
            for (int dk = 0; dk < DCC / 4; dk++) {
                int d = dk * 4;
                float4 a[4];
#pragma unroll
                for (int ri = 0; ri < 4; ri++) a[ri] = *(const float4*)&r_s[ty * 4 + ri][d];
                // two half-tiles of 4 codes each: keeps live b-regs at 16
#pragma unroll
                for (int h = 0; h < 2; h++) {
                    float4 b[4];
#pragma unroll
                    for (int j = 0; j < 4; j++)
                        b[j] = *(const float4*)&cb_s[tx + 32 * (4 * h + j)][d];
#pragma unroll
                    for (int ri = 0; ri < 4; ri++) {
#pragma unroll
                        for (int j = 0; j < 4; j++) {
                            float s = acc[ri][4 * h + j];
                            s = fmaf(a[ri].x, b[j].x, s);
                            s = fmaf(a[ri].y, b[j].y, s);
                            s = fmaf(a[ri].z, b[j].z, s);
                            s = fmaf(a[ri].w, b[j].w, s);
                            acc[ri][4 * h + j] = s;
                        }
                    }
                }
            }
        }

        // distances + running argmin for this code tile
        float nrm[8];
        int cid[8];
#pragma unroll
        for (int j = 0; j < 8; j++) {
            cid[j] = cbase + tx + 32 * j;
            nrm[j] = normq[cid[j]];
        }
#pragma unroll
        for (int ri = 0; ri < 4; ri++) {
            float d_ = nrm[0] - 2.0f * acc[ri][0];
            int i_ = cid[0];
#pragma unroll
            for (int j = 1; j < 8; j++) {      // ascending code index: tie -> lower
                float dj = nrm[j] - 2.0f * acc[ri][j];
                if (dj < d_ || (dj == d_ && cid[j] < i_)) { d_ = dj; i_ = cid[j]; }
            }
            // butterfly over the 32 tx-lanes (bit5 = ty parity untouched)
#pragma unroll
            for (int m = 1; m <= 16; m <<= 1) {
                float od = __shfl_xor(d_, m);
                int oi = __shfl_xor(i_, m);
                if (od < d_ || (od == d_ && oi < i_)) { d_ = od; i_ = oi; }
            }
            if (d_ < bd[ri] || (d_ == bd[ri] && i_ < bi[ri])) { bd[ri] = d_; bi[ri] = i_; }
        }
    }

    if (tx == 0) {
#pragma unroll
        for (int ri = 0; ri < 4; ri++) {
            int row = ty * 4 + ri;
            s_idx[row] = bi[ri];
            idx_out[(size_t)(row0 + row) * QD + q] = (float)bi[ri];
        }
    }
    __syncthreads();

    // ---- update phase: resid_new = r - cb[idx]; loss += ||resid_new||^2
    double ls = 0.0;
#pragma unroll 4
    for (int i = 0; i < 16; i++) {
        int flat = tid + TPB * i;          // 0..8191 float4 chunks
        int row = flat >> 7;               // 128 float4 per row
        int c4 = (flat & 127) * 4;
        size_t g = (size_t)(row0 + row) * DDIM + c4;
        float4 r = *(const float4*)(rsrc + g);
        if (qsub) {
            float4 w = *(const float4*)(qsub + g);
            r.x -= w.x; r.y -= w.y; r.z -= w.z; r.w -= w.w;
        }
        float4 cv = *(const float4*)(cbq + (size_t)s_idx[row] * DDIM + c4);
        float4 nr;
        nr.x = r.x - cv.x; nr.y = r.y - cv.y; nr.z = r.z - cv.z; nr.w = r.w - cv.w;
        if (resid) {
            *(float4*)(resid + g) = nr;
        } else {
            float4 qo = *(float4*)(quant + g);
            qo.x += cv.x; qo.y += cv.y; qo.z += cv.z; qo.w += cv.w;
            *(float4*)(quant + g) = qo;
        }
        ls += (double)nr.x * nr.x + (double)nr.y * nr.y +
              (double)nr.z * nr.z + (double)nr.w * nr.w;
    }
#pragma unroll
    for (int m = 32; m >= 1; m >>= 1) ls += __shfl_down(ls, m);
    if ((tid & 63) == 0) s_part[tid >> 6] = ls;
    __syncthreads();
    if (tid == 0) {
        double t = 0.0;
#pragma unroll
        for (int w = 0; w < 8; w++) t += s_part[w];
        atomicAdd(lossq, t);
    }
}

// ---------------------------------------------------------------- quant = x - resid_final
__global__ __launch_bounds__(256) void vq_quant_final(const float* __restrict__ x,
                                                      const float* __restrict__ resid,
                                                      float* __restrict__ quant) {
    size_t i = ((size_t)blockIdx.x * 256 + threadIdx.x) * 4;
    float4 xv = *(const float4*)(x + i);
    float4 rv = *(const float4*)(resid + i);
    float4 o;
    o.x = xv.x - rv.x; o.y = xv.y - rv.y; o.z = xv.z - rv.z; o.w = xv.w - rv.w;
    *(float4*)(quant + i) = o;
}

// ---------------------------------------------------------------- finalize losses
__global__ void vq_loss_final(const double* __restrict__ lossws, float* __restrict__ out) {
    int i = threadIdx.x;
    if (i < QD) out[i] = (float)(lossws[i] * (1.0 / (double)((size_t)ROWS * DDIM)));
}

// ---------------------------------------------------------------- launch
extern "C" void kernel_launch(void* const* d_in, const int* in_sizes, int n_in,
                              void* d_out, int out_size, void* d_ws, size_t ws_size,
                              hipStream_t stream) {
    const float* x = (const float*)d_in[0];
    const float* cbs = (const float*)d_in[1];
    float* out = (float*)d_out;
    float* quant = out;
    float* idxo = out + IDX_OFF;
    float* losso = out + LOSS_OFF;

    double* lossws = (double*)d_ws;
    float* norms = (float*)((char*)d_ws + WS_NORM_OFF);
    size_t residNeed = (size_t)WS_RESID_OFF + (size_t)QUANT_ELEMS * 4;
    float* resid = (ws_size >= residNeed) ? (float*)((char*)d_ws + WS_RESID_OFF) : nullptr;

    hipMemsetAsync(d_ws, 0, 64, stream);
    if (!resid) hipMemsetAsync(d_out, 0, (size_t)out_size * 4, stream);

    vq_norms<<<QD * CDN / 4, 256, 0, stream>>>(cbs, norms);

    for (int q = 0; q < QD; q++) {
        const float* cbq = cbs + (size_t)q * CDN * DDIM;
        const float* nq = norms + (size_t)q * CDN;
        const float* rsrc;
        const float* qsubA;
        if (resid) {
            rsrc = (q == 0) ? x : resid;
            qsubA = nullptr;
        } else {
            rsrc = x;
            qsubA = quant;  // r = x - quant (quant zeroed at start)
        }
        vq_level<<<ROWS / RPB, TPB, 0, stream>>>(rsrc, qsubA,
                                                 resid ? resid : nullptr, quant,
                                                 cbq, nq, idxo, lossws + q, q);
    }
    if (resid) {
        vq_quant_final<<<QUANT_ELEMS / 1024, 256, 0, stream>>>(x, resid, quant);
    }
    vq_loss_final<<<1, 64, 0, stream>>>(lossws, losso);
}

// Round 5
// 2061.115 us; speedup vs baseline: 4.9903x; 2.6419x over previous
//
#include <hip/hip_runtime.h>

// Problem constants (fixed by the reference)
#define BD 8
#define SD 4096
#define DDIM 512
#define QD 8
#define CDN 1024
#define ROWS (BD * SD)              // 32768
#define QUANT_ELEMS (ROWS * DDIM)   // 16777216
#define IDX_OFF QUANT_ELEMS
#define LOSS_OFF (QUANT_ELEMS + ROWS * QD)

#define TPB 512
#define BR 128                      // rows per block
#define CT 256                      // codes per ct-iter
#define NCT 4
#define NKC 16                      // K chunks of 32
#define ASTR 40                     // LDS A stride in ushorts (80 B: 16B-aligned, bank-balanced)
// 3-MFMA split (ah*bh + ah*bl + al*bh): max dist error ~2e-3 << MARGIN/2.
#define MARGIN 0.25f

// ws layout (bytes)
#define WS_LOSS 0                   // 8 doubles
#define WS_FBCNT 64                 // 8 ints
#define WS_FBLIST 4096              // 32768 ints (128 KB)
#define WS_NORMS 0x40000            // 32 KB
#define WS_PKHI 0x80000             // 1 MB
#define WS_PKLO 0x180000            // 1 MB
#define WS_RESID 0x280000           // 64 MB

typedef __attribute__((ext_vector_type(8))) short short8;
typedef __attribute__((ext_vector_type(4))) float f32x4;

__device__ __forceinline__ ushort f2bf(float x) {
    unsigned u = __float_as_uint(x);
    u += 0x7fff + ((u >> 16) & 1);          // RTNE
    return (ushort)(u >> 16);
}

// ---------------------------------------------------------------- norms
__global__ __launch_bounds__(256) void vq_norms(const float* __restrict__ cb,
                                                float* __restrict__ norms) {
    int code = blockIdx.x * 4 + (threadIdx.x >> 6);
    int lane = threadIdx.x & 63;
    const float4* p = (const float4*)(cb + (size_t)code * DDIM);
    float4 a = p[lane];
    float4 b = p[lane + 64];
    float s = a.x * a.x + a.y * a.y + a.z * a.z + a.w * a.w +
              b.x * b.x + b.y * b.y + b.z * b.z + b.w * b.w;
#pragma unroll
    for (int m = 32; m >= 1; m >>= 1) s += __shfl_xor(s, m);
    if (lane == 0) norms[code] = s;
}

// ---------------------------------------------------------------- cb pack (per level)
// Frag-major bf16 hi/lo: slot s = ((tile*16+kc)*64+lane); covers code=tile*16+(lane&15),
// k = kc*32 + (lane>>4)*8 + j.  Wave B-load = 64 lanes x 16B contiguous.
__global__ __launch_bounds__(256) void vq_cbpack(const float* __restrict__ cbq,
                                                 ushort* __restrict__ pkHi,
                                                 ushort* __restrict__ pkLo) {
    int s = blockIdx.x * 256 + threadIdx.x;    // 0..65535
    int tile = s >> 10;
    int kc = (s >> 6) & 15;
    int ln = s & 63;
    int code = tile * 16 + (ln & 15);
    int k0 = kc * 32 + (ln >> 4) * 8;
    const float* p = cbq + (size_t)code * DDIM + k0;
    float f[8];
    *(float4*)&f[0] = *(const float4*)p;
    *(float4*)&f[4] = *(const float4*)(p + 4);
    ushort h[8], l[8];
#pragma unroll
    for (int i = 0; i < 8; i++) {
        h[i] = f2bf(f[i]);
        float hf = __uint_as_float(((unsigned)h[i]) << 16);
        l[i] = f2bf(f[i] - hf);                // f - hf exact (Sterbenz)
    }
    *(short8*)(pkHi + (size_t)s * 8) = *(short8*)h;
    *(short8*)(pkLo + (size_t)s * 8) = *(short8*)l;
}

// ---------------------------------------------------------------- fused level (MFMA)
__global__ __launch_bounds__(TPB, 2) void vq_level_mfma(
    const float* __restrict__ rsrc, const float* __restrict__ qsub,
    float* __restrict__ resid, float* __restrict__ quant,
    const float* __restrict__ cbq, const float* __restrict__ normq,
    const ushort* __restrict__ pkHi, const ushort* __restrict__ pkLo,
    float* __restrict__ idx_out, double* __restrict__ lossq,
    int* __restrict__ fbCnt, int* __restrict__ fbList, int q) {
    __shared__ ushort Ah[2][BR][ASTR];       // 20480 B (A hi)
    __shared__ ushort Al[2][BR][ASTR];       // 20480 B (A lo)
    __shared__ float s_nrm[CDN];             // 4 KB
    __shared__ float s_d1[BR], s_d2[BR], s_d3[BR];
    __shared__ int s_i1[BR], s_i2[BR], s_flag[BR];
    __shared__ double s_part[8];

    int tid = threadIdx.x;
    int lane = tid & 63;
    int l15 = lane & 15;
    int quad = lane >> 4;
    int wv = tid >> 6;
    int rg = wv >> 1;       // row group: 32 rows
    int cg = wv & 1;        // code half: 128 codes per ct-iter
    int row0 = blockIdx.x * BR;

    for (int i = tid; i < CDN; i += TPB) s_nrm[i] = normq[i];

    // per-lane top-3 per slot (rt*4+reg): d1<=d2<=d3 by (d,idx) lex for 1,2
    float td1[8], td2[8], td3[8];
    int ti1[8], ti2[8];
#pragma unroll
    for (int s = 0; s < 8; s++) { td1[s] = 3.4e38f; td2[s] = 3.4e38f; td3[s] = 3.4e38f; ti1[s] = 0; ti2[s] = 0; }

    // staging address
    int st_row = tid >> 2;          // 0..127
    int st_koff = (tid & 3) * 8;    // 0,8,16,24
    size_t st_base = (size_t)(row0 + st_row) * DDIM + st_koff;

    for (int ct = 0; ct < NCT; ct++) {
        f32x4 acc[2][8];
#pragma unroll
        for (int rt = 0; rt < 2; rt++)
#pragma unroll
            for (int j = 0; j < 8; j++) acc[rt][j] = (f32x4)0.0f;

        __syncthreads();
        // stage kc=0 into buf 0
        {
            float f[8];
            *(float4*)&f[0] = *(const float4*)(rsrc + st_base);
            *(float4*)&f[4] = *(const float4*)(rsrc + st_base + 4);
            if (qsub) {
                float4 w0 = *(const float4*)(qsub + st_base);
                float4 w1 = *(const float4*)(qsub + st_base + 4);
                f[0] -= w0.x; f[1] -= w0.y; f[2] -= w0.z; f[3] -= w0.w;
                f[4] -= w1.x; f[5] -= w1.y; f[6] -= w1.z; f[7] -= w1.w;
            }
            ushort h[8], l[8];
#pragma unroll
            for (int i = 0; i < 8; i++) {
                h[i] = f2bf(f[i]);
                float hf = __uint_as_float(((unsigned)h[i]) << 16);
                l[i] = f2bf(f[i] - hf);
            }
            *(short8*)&Ah[0][st_row][st_koff] = *(short8*)h;
            *(short8*)&Al[0][st_row][st_koff] = *(short8*)l;
        }
        __syncthreads();

        for (int kc = 0; kc < NKC; kc++) {
            int buf = kc & 1;
            float f[8];
            bool pref = (kc < NKC - 1);
            if (pref) {
                size_t g = st_base + (size_t)(kc + 1) * 32;
                *(float4*)&f[0] = *(const float4*)(rsrc + g);
                *(float4*)&f[4] = *(const float4*)(rsrc + g + 4);
                if (qsub) {
                    float4 w0 = *(const float4*)(qsub + g);
                    float4 w1 = *(const float4*)(qsub + g + 4);
                    f[0] -= w0.x; f[1] -= w0.y; f[2] -= w0.z; f[3] -= w0.w;
                    f[4] -= w1.x; f[5] -= w1.y; f[6] -= w1.z; f[7] -= w1.w;
                }
            }
            short8 a0h = *(short8*)&Ah[buf][rg * 32 + l15][quad * 8];
            short8 a0l = *(short8*)&Al[buf][rg * 32 + l15][quad * 8];
            short8 a1h = *(short8*)&Ah[buf][rg * 32 + 16 + l15][quad * 8];
            short8 a1l = *(short8*)&Al[buf][rg * 32 + 16 + l15][quad * 8];
#pragma unroll
            for (int j = 0; j < 8; j++) {
                int tile = ct * 16 + cg * 8 + j;
                size_t off = ((size_t)(tile * 16 + kc) * 64 + lane) * 8;
                short8 bh = *(const short8*)(pkHi + off);
                short8 bl = *(const short8*)(pkLo + off);
                acc[0][j] = __builtin_amdgcn_mfma_f32_16x16x32_bf16(a0h, bh, acc[0][j], 0, 0, 0);
                acc[0][j] = __builtin_amdgcn_mfma_f32_16x16x32_bf16(a0l, bh, acc[0][j], 0, 0, 0);
                acc[0][j] = __builtin_amdgcn_mfma_f32_16x16x32_bf16(a0h, bl, acc[0][j], 0, 0, 0);
                acc[1][j] = __builtin_amdgcn_mfma_f32_16x16x32_bf16(a1h, bh, acc[1][j], 0, 0, 0);
                acc[1][j] = __builtin_amdgcn_mfma_f32_16x16x32_bf16(a1l, bh, acc[1][j], 0, 0, 0);
                acc[1][j] = __builtin_amdgcn_mfma_f32_16x16x32_bf16(a1h, bl, acc[1][j], 0, 0, 0);
            }
            if (pref) {
                ushort h[8], l[8];
#pragma unroll
                for (int i = 0; i < 8; i++) {
                    h[i] = f2bf(f[i]);
                    float hf = __uint_as_float(((unsigned)h[i]) << 16);
                    l[i] = f2bf(f[i] - hf);
                }
                *(short8*)&Ah[1 - buf][st_row][st_koff] = *(short8*)h;
                *(short8*)&Al[1 - buf][st_row][st_koff] = *(short8*)l;
            }
            __syncthreads();
        }

        // in-lane top-3 update (codes ascending => tie keeps lowest index)
#pragma unroll
        for (int j = 0; j < 8; j++) {
            int code = ct * CT + cg * 128 + j * 16 + l15;
            float nrm = s_nrm[code];
#pragma unroll
            for (int rt = 0; rt < 2; rt++)
#pragma unroll
                for (int reg = 0; reg < 4; reg++) {
                    float v = nrm - 2.0f * acc[rt][j][reg];
                    int s = rt * 4 + reg;
                    bool b1 = v < td1[s];
                    bool b2 = v < td2[s];
                    bool b3 = v < td3[s];
                    td3[s] = b2 ? td2[s] : (b3 ? v : td3[s]);
                    ti2[s] = b1 ? ti1[s] : (b2 ? code : ti2[s]);
                    td2[s] = b1 ? td1[s] : (b2 ? v : td2[s]);
                    ti1[s] = b1 ? code : ti1[s];
                    td1[s] = b1 ? v : td1[s];
                }
        }
    }

    // butterfly merge over 16 l15-lanes (same quad => same rows)
#pragma unroll
    for (int m = 1; m <= 8; m <<= 1) {
#pragma unroll
        for (int s = 0; s < 8; s++) {
            float o1 = __shfl_xor(td1[s], m); int oi1 = __shfl_xor(ti1[s], m);
            float o2 = __shfl_xor(td2[s], m); int oi2 = __shfl_xor(ti2[s], m);
            float o3 = __shfl_xor(td3[s], m);
            bool aw = (td1[s] < o1) || (td1[s] == o1 && ti1[s] < oi1);
            float w2 = aw ? td2[s] : o2; int wi2 = aw ? ti2[s] : oi2;
            float w3 = aw ? td3[s] : o3;
            float n1 = aw ? td1[s] : o1; int ni1 = aw ? ti1[s] : oi1;
            float p1 = aw ? o1 : td1[s]; int pi1 = aw ? oi1 : ti1[s];
            float p2 = aw ? o2 : td2[s];
            bool sw = (w2 < p1) || (w2 == p1 && wi2 < pi1);
            float n2 = sw ? w2 : p1; int ni2 = sw ? wi2 : pi1;
            float n3 = sw ? fminf(p1, w3) : fminf(w2, p2);
            td1[s] = n1; ti1[s] = ni1; td2[s] = n2; ti2[s] = ni2; td3[s] = n3;
        }
    }

    if (cg == 0 && l15 == 0) {
#pragma unroll
        for (int s = 0; s < 8; s++) {
            int r = rg * 32 + (s >> 2) * 16 + quad * 4 + (s & 3);
            s_d1[r] = td1[s]; s_i1[r] = ti1[s]; s_d2[r] = td2[s]; s_i2[r] = ti2[s]; s_d3[r] = td3[s];
        }
    }
    __syncthreads();
    if (cg == 1 && l15 == 0) {
#pragma unroll
        for (int s = 0; s < 8; s++) {
            int r = rg * 32 + (s >> 2) * 16 + quad * 4 + (s & 3);
            float o1 = s_d1[r]; int oi1 = s_i1[r];
            float o2 = s_d2[r]; int oi2 = s_i2[r];
            float o3 = s_d3[r];
            bool aw = (td1[s] < o1) || (td1[s] == o1 && ti1[s] < oi1);
            float w2 = aw ? td2[s] : o2; int wi2 = aw ? ti2[s] : oi2;
            float w3 = aw ? td3[s] : o3;
            float n1 = aw ? td1[s] : o1; int ni1 = aw ? ti1[s] : oi1;
            float p1 = aw ? o1 : td1[s]; int pi1 = aw ? oi1 : ti1[s];
            float p2 = aw ? o2 : td2[s];
            bool sw = (w2 < p1) || (w2 == p1 && wi2 < pi1);
            float n2 = sw ? w2 : p1; int ni2 = sw ? wi2 : pi1;
            float n3 = sw ? fminf(p1, w3) : fminf(w2, p2);
            int flag = 0;
            if (n3 - n1 < MARGIN) flag = 2;          // >=3 candidates: full fallback
            else if (n2 - n1 < MARGIN) flag = 1;     // 2 candidates: exact rescore here
            s_i1[r] = ni1; s_i2[r] = ni2; s_flag[r] = flag;
            if (flag == 2) {
                int p = atomicAdd(fbCnt, 1);
                if (p < 32768) fbList[p] = row0 + r;
            }
        }
    }
    __syncthreads();

    // exact fp32 rescore of 2-candidate rows (wave-cooperative)
    for (int r = wv; r < BR; r += 8) {
        if (s_flag[r] != 1) continue;
        int i1 = s_i1[r], i2 = s_i2[r];
        size_t g = (size_t)(row0 + r) * DDIM + lane * 8;
        float rv[8];
        *(float4*)&rv[0] = *(const float4*)(rsrc + g);
        *(float4*)&rv[4] = *(const float4*)(rsrc + g + 4);
        if (qsub) {
            float4 w0 = *(const float4*)(qsub + g);
            float4 w1 = *(const float4*)(qsub + g + 4);
            rv[0] -= w0.x; rv[1] -= w0.y; rv[2] -= w0.z; rv[3] -= w0.w;
            rv[4] -= w1.x; rv[5] -= w1.y; rv[6] -= w1.z; rv[7] -= w1.w;
        }
        float c1[8], c2[8];
        *(float4*)&c1[0] = *(const float4*)(cbq + (size_t)i1 * DDIM + lane * 8);
        *(float4*)&c1[4] = *(const float4*)(cbq + (size_t)i1 * DDIM + lane * 8 + 4);
        *(float4*)&c2[0] = *(const float4*)(cbq + (size_t)i2 * DDIM + lane * 8);
        *(float4*)&c2[4] = *(const float4*)(cbq + (size_t)i2 * DDIM + lane * 8 + 4);
        float e1 = 0.0f, e2 = 0.0f;
#pragma unroll
        for (int i = 0; i < 8; i++) { e1 = fmaf(rv[i], c1[i], e1); e2 = fmaf(rv[i], c2[i], e2); }
#pragma unroll
        for (int m = 32; m >= 1; m >>= 1) { e1 += __shfl_xor(e1, m); e2 += __shfl_xor(e2, m); }
        float dd1 = s_nrm[i1] - 2.0f * e1;
        float dd2 = s_nrm[i2] - 2.0f * e2;
        bool take2 = (dd2 < dd1) || (dd2 == dd1 && i2 < i1);
        if (lane == 0) s_i1[r] = take2 ? i2 : i1;
    }
    __syncthreads();

    // idx writes
    if (tid < BR) idx_out[(size_t)(row0 + tid) * QD + q] = (float)s_i1[tid];

    // update phase: resid_new = r - cb[idx]; loss += ||resid_new||^2 (skip fallback rows)
    double ls = 0.0;
#pragma unroll 4
    for (int it = 0; it < 32; it++) {
        int flat = tid + TPB * it;
        int row = flat >> 7;
        int c4 = (flat & 127) * 4;
        if (s_flag[row] == 2) continue;
        size_t g = (size_t)(row0 + row) * DDIM + c4;
        float4 r = *(const float4*)(rsrc + g);
        if (qsub) {
            float4 w = *(const float4*)(qsub + g);
            r.x -= w.x; r.y -= w.y; r.z -= w.z; r.w -= w.w;
        }
        float4 cv = *(const float4*)(cbq + (size_t)s_i1[row] * DDIM + c4);
        float4 nr;
        nr.x = r.x - cv.x; nr.y = r.y - cv.y; nr.z = r.z - cv.z; nr.w = r.w - cv.w;
        if (resid) {
            *(float4*)(resid + g) = nr;
        } else {
            float4 qo = *(float4*)(quant + g);
            qo.x += cv.x; qo.y += cv.y; qo.z += cv.z; qo.w += cv.w;
            *(float4*)(quant + g) = qo;
        }
        ls += (double)nr.x * nr.x + (double)nr.y * nr.y +
              (double)nr.z * nr.z + (double)nr.w * nr.w;
    }
#pragma unroll
    for (int m = 32; m >= 1; m >>= 1) ls += __shfl_down(ls, m);
    if ((tid & 63) == 0) s_part[tid >> 6] = ls;
    __syncthreads();
    if (tid == 0) {
        double t = 0.0;
#pragma unroll
        for (int w = 0; w < 8; w++) t += s_part[w];
        atomicAdd(lossq, t);
    }
}

// ---------------------------------------------------------------- full-scan fallback (rare rows)
__global__ __launch_bounds__(256) void vq_fallback(
    const float* __restrict__ rsrc, const float* __restrict__ qsub,
    float* __restrict__ resid, float* __restrict__ quant,
    const float* __restrict__ cbq, const float* __restrict__ normq,
    float* __restrict__ idx_out, double* __restrict__ lossq,
    const int* __restrict__ fbCnt, const int* __restrict__ fbList, int q) {
    __shared__ float r_s[DDIM];
    __shared__ unsigned long long s_best;
    int tid = threadIdx.x;
    int n = *fbCnt; if (n > 32768) n = 32768;
    for (int w = blockIdx.x; w < n; w += gridDim.x) {
        int row = fbList[w];
        if (tid == 0) s_best = ~0ull;
        if (tid < 128) {
            size_t g = (size_t)row * DDIM + tid * 4;
            float4 v = *(const float4*)(rsrc + g);
            if (qsub) {
                float4 x = *(const float4*)(qsub + g);
                v.x -= x.x; v.y -= x.y; v.z -= x.z; v.w -= x.w;
            }
            *(float4*)&r_s[tid * 4] = v;
        }
        __syncthreads();
#pragma unroll
        for (int cc = 0; cc < 4; cc++) {
            int c = tid + 256 * cc;
            float dot = 0.0f;
            for (int k4 = 0; k4 < 128; k4++) {
                float4 cv = *(const float4*)(cbq + (size_t)c * DDIM + k4 * 4);
                float4 rv = *(const float4*)&r_s[k4 * 4];
                dot = fmaf(cv.x, rv.x, dot); dot = fmaf(cv.y, rv.y, dot);
                dot = fmaf(cv.z, rv.z, dot); dot = fmaf(cv.w, rv.w, dot);
            }
            float dist = normq[c] - 2.0f * dot;
            unsigned b = __float_as_uint(dist);
            b = (b & 0x80000000u) ? ~b : (b | 0x80000000u);   // monotone key
            unsigned long long key = (((unsigned long long)b) << 32) | (unsigned)c;
            atomicMin(&s_best, key);
        }
        __syncthreads();
        int idx = (int)(s_best & 0xffffffffull);
        if (tid == 0) idx_out[(size_t)row * QD + q] = (float)idx;
        double ls = 0.0;
        if (tid < 128) {
            size_t g = (size_t)row * DDIM + tid * 4;
            float4 r = *(const float4*)&r_s[tid * 4];
            float4 cv = *(const float4*)(cbq + (size_t)idx * DDIM + tid * 4);
            float4 nr;
            nr.x = r.x - cv.x; nr.y = r.y - cv.y; nr.z = r.z - cv.z; nr.w = r.w - cv.w;
            if (resid) {
                *(float4*)(resid + g) = nr;
            } else {
                float4 qo = *(float4*)(quant + g);
                qo.x += cv.x; qo.y += cv.y; qo.z += cv.z; qo.w += cv.w;
                *(float4*)(quant + g) = qo;
            }
            ls = (double)nr.x * nr.x + (double)nr.y * nr.y +
                 (double)nr.z * nr.z + (double)nr.w * nr.w;
        }
#pragma unroll
        for (int m = 32; m >= 1; m >>= 1) ls += __shfl_down(ls, m);
        if ((tid & 63) == 0 && ls != 0.0) atomicAdd(lossq, ls);
        __syncthreads();
    }
}

// ---------------------------------------------------------------- quant = x - resid_final
__global__ __launch_bounds__(256) void vq_quant_final(const float* __restrict__ x,
                                                      const float* __restrict__ resid,
                                                      float* __restrict__ quant) {
    size_t i = ((size_t)blockIdx.x * 256 + threadIdx.x) * 4;
    float4 xv = *(const float4*)(x + i);
    float4 rv = *(const float4*)(resid + i);
    float4 o;
    o.x = xv.x - rv.x; o.y = xv.y - rv.y; o.z = xv.z - rv.z; o.w = xv.w - rv.w;
    *(float4*)(quant + i) = o;
}

// ---------------------------------------------------------------- finalize losses
__global__ void vq_loss_final(const double* __restrict__ lossws, float* __restrict__ out) {
    int i = threadIdx.x;
    if (i < QD) out[i] = (float)(lossws[i] * (1.0 / (double)((size_t)ROWS * DDIM)));
}

// ---------------------------------------------------------------- launch
extern "C" void kernel_launch(void* const* d_in, const int* in_sizes, int n_in,
                              void* d_out, int out_size, void* d_ws, size_t ws_size,
                              hipStream_t stream) {
    const float* x = (const float*)d_in[0];
    const float* cbs = (const float*)d_in[1];
    float* out = (float*)d_out;
    float* quant = out;
    float* idxo = out + IDX_OFF;
    float* losso = out + LOSS_OFF;

    char* ws = (char*)d_ws;
    double* lossws = (double*)(ws + WS_LOSS);
    int* fbCnt = (int*)(ws + WS_FBCNT);
    int* fbList = (int*)(ws + WS_FBLIST);
    float* norms = (float*)(ws + WS_NORMS);
    ushort* pkHi = (ushort*)(ws + WS_PKHI);
    ushort* pkLo = (ushort*)(ws + WS_PKLO);
    float* resid = (ws_size >= (size_t)WS_RESID + (size_t)QUANT_ELEMS * 4)
                       ? (float*)(ws + WS_RESID) : nullptr;

    hipMemsetAsync(d_ws, 0, 128, stream);           // loss + fb counters
    if (!resid) hipMemsetAsync(d_out, 0, (size_t)out_size * 4, stream);

    vq_norms<<<QD * CDN / 4, 256, 0, stream>>>(cbs, norms);

    for (int q = 0; q < QD; q++) {
        const float* cbq = cbs + (size_t)q * CDN * DDIM;
        const float* nq = norms + (size_t)q * CDN;
        const float* rsrc;
        const float* qsubA;
        if (resid) {
            rsrc = (q == 0) ? x : resid;
            qsubA = nullptr;
        } else {
            rsrc = x;
            qsubA = quant;
        }
        vq_cbpack<<<256, 256, 0, stream>>>(cbq, pkHi, pkLo);
        vq_level_mfma<<<ROWS / BR, TPB, 0, stream>>>(
            rsrc, qsubA, resid, quant, cbq, nq, pkHi, pkLo,
            idxo, lossws + q, fbCnt + q, fbList, q);
        vq_fallback<<<128, 256, 0, stream>>>(
            rsrc, qsubA, resid, quant, cbq, nq, idxo, lossws + q,
            fbCnt + q, fbList, q);
    }
    if (resid) {
        vq_quant_final<<<QUANT_ELEMS / 1024, 256, 0, stream>>>(x, resid, quant);
    }
    vq_loss_final<<<1, 64, 0, stream>>>(lossws, losso);
}